// Round 1
// baseline (4644.620 us; speedup 1.0000x reference)
//
#include <hip/hip_runtime.h>

// Problem constants (derived/fixed from reference setup_inputs):
// B=2, L=10000, H=8, E=64, NE=160000
#define BB 2
#define HH 8
#define EE 64

// ---------- pass 1: qk dot + segment max ----------
// one wave per (edge, b). lane = h*8 + j ; lane reads 8 consecutive floats
// (2 float4) of q[b,dst,h,:] and k[b,src,h,:] -> coalesced 2KB row per wave.
__global__ __launch_bounds__(256) void qk_max_kernel(
    const float* __restrict__ q, const float* __restrict__ k,
    const int* __restrict__ dst, const int* __restrict__ src,
    float* __restrict__ qk, unsigned int* __restrict__ segmax,
    int NE, int L) {
  int wid = blockIdx.x * (blockDim.x >> 6) + (threadIdx.x >> 6);
  int lane = threadIdx.x & 63;
  if (wid >= NE * BB) return;
  int e = wid >> 1;      // / BB
  int b = wid & 1;
  int d = dst[e];
  int s = src[e];
  int h = lane >> 3;
  int j = lane & 7;
  const float4* qrow = (const float4*)(q + ((size_t)b * L + d) * (HH * EE));
  const float4* krow = (const float4*)(k + ((size_t)b * L + s) * (HH * EE));
  float4 qa = qrow[lane * 2 + 0];
  float4 qb = qrow[lane * 2 + 1];
  float4 ka = krow[lane * 2 + 0];
  float4 kb = krow[lane * 2 + 1];
  float p = qa.x * ka.x + qa.y * ka.y + qa.z * ka.z + qa.w * ka.w +
            qb.x * kb.x + qb.y * kb.y + qb.z * kb.z + qb.w * kb.w;
  // reduce over j (lanes differ in bits 0..2)
  p += __shfl_xor(p, 1);
  p += __shfl_xor(p, 2);
  p += __shfl_xor(p, 4);
  if (j == 0) {
    float val = p * 0.125f;  // softmax_temp = 1/sqrt(64)
    qk[((size_t)e * BB + b) * HH + h] = val;
    // monotone float->uint mapping for atomicMax
    unsigned int u = __float_as_uint(val);
    u = (u & 0x80000000u) ? ~u : (u | 0x80000000u);
    atomicMax(&segmax[((size_t)d * BB + b) * HH + h], u);
  }
}

// ---------- pass 2: exp(qk - max) + segment sum ----------
__global__ __launch_bounds__(256) void ex_sum_kernel(
    const int* __restrict__ dst, float* __restrict__ qk,
    const unsigned int* __restrict__ segmax, float* __restrict__ segsum,
    int NE) {
  int i = blockIdx.x * blockDim.x + threadIdx.x;  // over NE*B*H
  if (i >= NE * (BB * HH)) return;
  int e = i >> 4;        // / (B*H)
  int bh = i & 15;
  int d = dst[e];
  unsigned int u = segmax[(size_t)d * (BB * HH) + bh];
  float m = (u & 0x80000000u) ? __uint_as_float(u ^ 0x80000000u)
                              : __uint_as_float(~u);
  float ex = __expf(qk[i] - m);
  qk[i] = ex;
  atomicAdd(&segsum[(size_t)d * (BB * HH) + bh], ex);
}

// ---------- pass 3: out[b,dst,h,:] += alpha * v[b,src,h,:] ----------
__global__ __launch_bounds__(256) void scatter_kernel(
    const float* __restrict__ v, const int* __restrict__ dst,
    const int* __restrict__ src, const float* __restrict__ exq,
    const float* __restrict__ segsum, float* __restrict__ out,
    int NE, int L) {
  int wid = blockIdx.x * (blockDim.x >> 6) + (threadIdx.x >> 6);
  int lane = threadIdx.x & 63;
  if (wid >= NE * BB) return;
  int e = wid >> 1;
  int b = wid & 1;
  int d = dst[e];
  int s = src[e];
  int h = lane >> 3;
  float alpha = exq[((size_t)e * BB + b) * HH + h] /
                (segsum[((size_t)d * BB + b) * HH + h] + 1e-16f);
  const float4* vrow = (const float4*)(v + ((size_t)b * L + s) * (HH * EE));
  float4 va = vrow[lane * 2 + 0];
  float4 vb = vrow[lane * 2 + 1];
  float* orow = out + ((size_t)b * L + d) * (HH * EE) + lane * 8;
  atomicAdd(orow + 0, va.x * alpha);
  atomicAdd(orow + 1, va.y * alpha);
  atomicAdd(orow + 2, va.z * alpha);
  atomicAdd(orow + 3, va.w * alpha);
  atomicAdd(orow + 4, vb.x * alpha);
  atomicAdd(orow + 5, vb.y * alpha);
  atomicAdd(orow + 6, vb.z * alpha);
  atomicAdd(orow + 7, vb.w * alpha);
}

extern "C" void kernel_launch(void* const* d_in, const int* in_sizes, int n_in,
                              void* d_out, int out_size, void* d_ws, size_t ws_size,
                              hipStream_t stream) {
  const float* q = (const float*)d_in[0];
  const float* k = (const float*)d_in[1];
  const float* v = (const float*)d_in[2];
  const int* adj = (const int*)d_in[3];

  const int NE = in_sizes[3] / 2;
  const int L = in_sizes[0] / (BB * HH * EE);
  const int* dst = adj;        // adj[0, :]
  const int* src = adj + NE;   // adj[1, :]

  // workspace layout
  char* ws = (char*)d_ws;
  float* qk = (float*)ws;                                   // NE*B*H floats
  size_t qk_bytes = (size_t)NE * BB * HH * sizeof(float);
  unsigned int* segmax = (unsigned int*)(ws + qk_bytes);    // L*B*H uints
  size_t seg_bytes = (size_t)L * BB * HH * sizeof(unsigned int);
  float* segsum = (float*)(ws + qk_bytes + seg_bytes);      // L*B*H floats

  // init: out = 0 (empty segments must be zero), segmax = encoded-min, segsum = 0
  hipMemsetAsync(d_out, 0, (size_t)out_size * sizeof(float), stream);
  hipMemsetAsync(segmax, 0, seg_bytes, stream);
  hipMemsetAsync(segsum, 0, seg_bytes, stream);

  float* out = (float*)d_out;

  const int waves_per_block = 4;  // 256 threads
  int nwaves = NE * BB;
  int blocks_wave = (nwaves + waves_per_block - 1) / waves_per_block;

  qk_max_kernel<<<blocks_wave, 256, 0, stream>>>(q, k, dst, src, qk, segmax, NE, L);

  int nelem = NE * BB * HH;
  int blocks_elem = (nelem + 255) / 256;
  ex_sum_kernel<<<blocks_elem, 256, 0, stream>>>(dst, qk, segmax, segsum, NE);

  scatter_kernel<<<blocks_wave, 256, 0, stream>>>(v, dst, src, qk, segsum, out, NE, L);
}

// Round 2
// 444.828 us; speedup vs baseline: 10.4414x; 10.4414x over previous
//
#include <hip/hip_runtime.h>

// Problem constants (from reference setup_inputs): B=2, L=10000, H=8, E=64, NE=160000
#define BB 2
#define HH 8
#define EE 64

// ---------- CSR build over dst ----------
__global__ __launch_bounds__(256) void hist_kernel(
    const int* __restrict__ dst, int* __restrict__ counts, int NE) {
  int e = blockIdx.x * blockDim.x + threadIdx.x;
  if (e >= NE) return;
  atomicAdd(&counts[dst[e]], 1);
}

// single-block exclusive scan over L (~10000) counts -> offsets[0..L]
__global__ __launch_bounds__(1024) void scan_kernel(
    const int* __restrict__ counts, int* __restrict__ offsets, int L) {
  __shared__ int sums[1024];
  int tid = threadIdx.x;
  int chunk = (L + 1023) / 1024;
  int beg = tid * chunk;
  int end = min(beg + chunk, L);
  int s = 0;
  for (int i = beg; i < end; ++i) s += counts[i];
  sums[tid] = s;
  __syncthreads();
  for (int off = 1; off < 1024; off <<= 1) {
    int val = 0;
    if (tid >= off) val = sums[tid - off];
    __syncthreads();
    if (tid >= off) sums[tid] += val;
    __syncthreads();
  }
  int run = (tid > 0) ? sums[tid - 1] : 0;  // exclusive prefix of this chunk
  for (int i = beg; i < end; ++i) {
    offsets[i] = run;
    run += counts[i];
  }
  if (tid == 1023) offsets[L] = run;  // == NE
}

__global__ __launch_bounds__(256) void fill_csr_kernel(
    const int* __restrict__ dst, const int* __restrict__ offsets,
    int* __restrict__ cursor, int* __restrict__ edge_ids, int NE) {
  int e = blockIdx.x * blockDim.x + threadIdx.x;
  if (e >= NE) return;
  int d = dst[e];
  int pos = atomicAdd(&cursor[d], 1);
  edge_ids[offsets[d] + pos] = e;
}

// ---------- pass 1: qk dot + segment max ----------
// one wave per (edge, b). lane = h*8+j; wave reads full 2KB [H,E] rows coalesced.
__global__ __launch_bounds__(256) void qk_max_kernel(
    const float* __restrict__ q, const float* __restrict__ k,
    const int* __restrict__ dst, const int* __restrict__ src,
    float* __restrict__ qk, unsigned int* __restrict__ segmax,
    int NE, int L) {
  int wid = blockIdx.x * (blockDim.x >> 6) + (threadIdx.x >> 6);
  int lane = threadIdx.x & 63;
  if (wid >= NE * BB) return;
  int e = wid >> 1;
  int b = wid & 1;
  int d = dst[e];
  int s = src[e];
  int h = lane >> 3;
  int j = lane & 7;
  const float4* qrow = (const float4*)(q + ((size_t)b * L + d) * (HH * EE));
  const float4* krow = (const float4*)(k + ((size_t)b * L + s) * (HH * EE));
  float4 qa = qrow[lane * 2 + 0];
  float4 qb = qrow[lane * 2 + 1];
  float4 ka = krow[lane * 2 + 0];
  float4 kb = krow[lane * 2 + 1];
  float p = qa.x * ka.x + qa.y * ka.y + qa.z * ka.z + qa.w * ka.w +
            qb.x * kb.x + qb.y * kb.y + qb.z * kb.z + qb.w * kb.w;
  p += __shfl_xor(p, 1);
  p += __shfl_xor(p, 2);
  p += __shfl_xor(p, 4);
  if (j == 0) {
    float val = p * 0.125f;  // softmax_temp = 1/sqrt(64)
    qk[((size_t)e * BB + b) * HH + h] = val;
    unsigned int u = __float_as_uint(val);
    u = (u & 0x80000000u) ? ~u : (u | 0x80000000u);  // monotone map
    atomicMax(&segmax[((size_t)d * BB + b) * HH + h], u);
  }
}

// ---------- pass 2: exp(qk - max) + segment sum ----------
__global__ __launch_bounds__(256) void ex_sum_kernel(
    const int* __restrict__ dst, float* __restrict__ qk,
    const unsigned int* __restrict__ segmax, float* __restrict__ segsum,
    int NE) {
  int i = blockIdx.x * blockDim.x + threadIdx.x;  // over NE*B*H
  if (i >= NE * (BB * HH)) return;
  int e = i >> 4;
  int bh = i & 15;
  int d = dst[e];
  unsigned int u = segmax[(size_t)d * (BB * HH) + bh];
  float m = (u & 0x80000000u) ? __uint_as_float(u ^ 0x80000000u)
                              : __uint_as_float(~u);
  float ex = __expf(qk[i] - m);
  qk[i] = ex;
  atomicAdd(&segsum[(size_t)d * (BB * HH) + bh], ex);
}

// ---------- pass 3 (CSR gather): out[b,d,h,:] = sum_e alpha * v[b,src,h,:] ----------
// one wave per (d, b). Accumulate the [H,E] row in registers, one store.
__global__ __launch_bounds__(256) void gather_out_kernel(
    const float* __restrict__ v, const int* __restrict__ src,
    const int* __restrict__ offsets, const int* __restrict__ edge_ids,
    const float* __restrict__ exq, const float* __restrict__ segsum,
    float* __restrict__ out, int L) {
  int wid = blockIdx.x * (blockDim.x >> 6) + (threadIdx.x >> 6);
  int lane = threadIdx.x & 63;
  if (wid >= L * BB) return;
  int d = wid >> 1;
  int b = wid & 1;
  int h = lane >> 3;
  int beg = offsets[d];
  int end = offsets[d + 1];
  float rsum = 1.0f / (segsum[((size_t)d * BB + b) * HH + h] + 1e-16f);
  float a0 = 0, a1 = 0, a2 = 0, a3 = 0, a4 = 0, a5 = 0, a6 = 0, a7 = 0;
  for (int t = beg; t < end; ++t) {
    int e = edge_ids[t];
    int s = src[e];
    float alpha = exq[((size_t)e * BB + b) * HH + h] * rsum;
    const float4* vrow = (const float4*)(v + ((size_t)b * L + s) * (HH * EE));
    float4 va = vrow[lane * 2 + 0];
    float4 vb = vrow[lane * 2 + 1];
    a0 += alpha * va.x; a1 += alpha * va.y; a2 += alpha * va.z; a3 += alpha * va.w;
    a4 += alpha * vb.x; a5 += alpha * vb.y; a6 += alpha * vb.z; a7 += alpha * vb.w;
  }
  float4* orow = (float4*)(out + ((size_t)b * L + d) * (HH * EE));
  orow[lane * 2 + 0] = make_float4(a0, a1, a2, a3);
  orow[lane * 2 + 1] = make_float4(a4, a5, a6, a7);
}

extern "C" void kernel_launch(void* const* d_in, const int* in_sizes, int n_in,
                              void* d_out, int out_size, void* d_ws, size_t ws_size,
                              hipStream_t stream) {
  const float* q = (const float*)d_in[0];
  const float* k = (const float*)d_in[1];
  const float* v = (const float*)d_in[2];
  const int* adj = (const int*)d_in[3];

  const int NE = in_sizes[3] / 2;
  const int L = in_sizes[0] / (BB * HH * EE);
  const int* dst = adj;
  const int* src = adj + NE;

  // workspace layout
  char* ws = (char*)d_ws;
  size_t off = 0;
  float* qk = (float*)(ws + off);           off += (size_t)NE * BB * HH * sizeof(float);   // 10.24 MB
  unsigned int* segmax = (unsigned int*)(ws + off); off += (size_t)L * BB * HH * 4;        // 640 KB
  float* segsum = (float*)(ws + off);       off += (size_t)L * BB * HH * 4;                // 640 KB
  int* counts = (int*)(ws + off);           off += (size_t)L * 4;
  int* offsets = (int*)(ws + off);          off += (size_t)(L + 1) * 4;
  int* cursor = (int*)(ws + off);           off += (size_t)L * 4;
  int* edge_ids = (int*)(ws + off);         off += (size_t)NE * 4;

  hipMemsetAsync(segmax, 0, (size_t)L * BB * HH * 4, stream);
  hipMemsetAsync(segsum, 0, (size_t)L * BB * HH * 4, stream);
  hipMemsetAsync(counts, 0, (size_t)L * 4, stream);
  hipMemsetAsync(cursor, 0, (size_t)L * 4, stream);

  float* out = (float*)d_out;

  // CSR build
  hist_kernel<<<(NE + 255) / 256, 256, 0, stream>>>(dst, counts, NE);
  scan_kernel<<<1, 1024, 0, stream>>>(counts, offsets, L);
  fill_csr_kernel<<<(NE + 255) / 256, 256, 0, stream>>>(dst, offsets, cursor, edge_ids, NE);

  // pass 1
  int nwaves = NE * BB;
  qk_max_kernel<<<(nwaves + 3) / 4, 256, 0, stream>>>(q, k, dst, src, qk, segmax, NE, L);

  // pass 2
  int nelem = NE * BB * HH;
  ex_sum_kernel<<<(nelem + 255) / 256, 256, 0, stream>>>(dst, qk, segmax, segsum, NE);

  // pass 3: gather per destination row
  int owaves = L * BB;
  gather_out_kernel<<<(owaves + 3) / 4, 256, 0, stream>>>(
      v, src, offsets, edge_ids, qk, segsum, out, L);
}

// Round 3
// 287.770 us; speedup vs baseline: 16.1400x; 1.5458x over previous
//
#include <hip/hip_runtime.h>

// Problem constants (from reference setup_inputs): B=2, L=10000, H=8, E=64, NE=160000
#define BB 2
#define HH 8
#define EE 64
#define ROW (HH * EE)      // 512 elements per (b, node) row
#define CHUNK 16

// ---------- fp32 -> bf16 (RNE) conversion of k and v ----------
__device__ inline unsigned short f2bf(float f) {
  unsigned int u = __float_as_uint(f);
  u = (u + 0x7fffu + ((u >> 16) & 1u)) >> 16;
  return (unsigned short)u;
}

__global__ __launch_bounds__(256) void convert_kernel(
    const float* __restrict__ k, const float* __restrict__ v,
    unsigned short* __restrict__ kbf, unsigned short* __restrict__ vbf,
    int n4) {  // n4 = total_elems / 4
  int i = blockIdx.x * blockDim.x + threadIdx.x;
  if (i >= n4) return;
  float4 kf = ((const float4*)k)[i];
  float4 vf = ((const float4*)v)[i];
  ushort4 ko = make_ushort4(f2bf(kf.x), f2bf(kf.y), f2bf(kf.z), f2bf(kf.w));
  ushort4 vo = make_ushort4(f2bf(vf.x), f2bf(vf.y), f2bf(vf.z), f2bf(vf.w));
  ((ushort4*)kbf)[i] = ko;
  ((ushort4*)vbf)[i] = vo;
}

// ---------- CSR build over dst ----------
__global__ __launch_bounds__(256) void hist_kernel(
    const int* __restrict__ dst, int* __restrict__ counts, int NE) {
  int e = blockIdx.x * blockDim.x + threadIdx.x;
  if (e >= NE) return;
  atomicAdd(&counts[dst[e]], 1);
}

__global__ __launch_bounds__(1024) void scan_kernel(
    const int* __restrict__ counts, int* __restrict__ offsets, int L) {
  __shared__ int sums[1024];
  int tid = threadIdx.x;
  int chunk = (L + 1023) / 1024;
  int beg = tid * chunk;
  int end = min(beg + chunk, L);
  int s = 0;
  for (int i = beg; i < end; ++i) s += counts[i];
  sums[tid] = s;
  __syncthreads();
  for (int off = 1; off < 1024; off <<= 1) {
    int val = 0;
    if (tid >= off) val = sums[tid - off];
    __syncthreads();
    if (tid >= off) sums[tid] += val;
    __syncthreads();
  }
  int run = (tid > 0) ? sums[tid - 1] : 0;
  for (int i = beg; i < end; ++i) {
    offsets[i] = run;
    run += counts[i];
  }
  if (tid == 1023) offsets[L] = run;
}

// store src node id directly (edge identity not needed downstream)
__global__ __launch_bounds__(256) void fill_csr_kernel(
    const int* __restrict__ dst, const int* __restrict__ src,
    const int* __restrict__ offsets, int* __restrict__ cursor,
    int* __restrict__ csr_src, int NE) {
  int e = blockIdx.x * blockDim.x + threadIdx.x;
  if (e >= NE) return;
  int d = dst[e];
  int pos = atomicAdd(&cursor[d], 1);
  csr_src[offsets[d] + pos] = src[e];
}

// ---------- fused flash-style kernel: one wave per (dst, b) ----------
// lane = h*8 + j covers elements 8*lane .. 8*lane+7 of the 512-elem [H,E] row.
// Butterfly reduce over j gives every lane in an h-group the full dot.
__device__ inline void bf8_unpack(uint4 u, float* f) {
  f[0] = __uint_as_float(u.x << 16);
  f[1] = __uint_as_float(u.x & 0xffff0000u);
  f[2] = __uint_as_float(u.y << 16);
  f[3] = __uint_as_float(u.y & 0xffff0000u);
  f[4] = __uint_as_float(u.z << 16);
  f[5] = __uint_as_float(u.z & 0xffff0000u);
  f[6] = __uint_as_float(u.w << 16);
  f[7] = __uint_as_float(u.w & 0xffff0000u);
}

__global__ __launch_bounds__(256) void fused_attn_kernel(
    const float* __restrict__ q, const unsigned short* __restrict__ kbf,
    const unsigned short* __restrict__ vbf, const int* __restrict__ offsets,
    const int* __restrict__ csr_src, float* __restrict__ out, int L) {
  int wid = blockIdx.x * (blockDim.x >> 6) + (threadIdx.x >> 6);
  int lane = threadIdx.x & 63;
  if (wid >= L * BB) return;
  int d = wid >> 1;
  int b = wid & 1;
  int beg = offsets[d];
  int end = offsets[d + 1];

  // q row (fp32): 8 floats per lane
  const float4* qrow = (const float4*)(q + ((size_t)b * L + d) * ROW);
  float4 q0 = qrow[lane * 2 + 0];
  float4 q1 = qrow[lane * 2 + 1];

  float m = -INFINITY;
  float l_run = 0.0f;
  float acc[8];
#pragma unroll
  for (int i = 0; i < 8; ++i) acc[i] = 0.0f;

  const uint4* kb_base = (const uint4*)(kbf + (size_t)b * L * ROW);
  const uint4* vb_base = (const uint4*)(vbf + (size_t)b * L * ROW);

  for (int t0 = beg; t0 < end; t0 += CHUNK) {
    int cnt = min(CHUNK, end - t0);
    float qk[CHUNK];
    int srcs[CHUNK];
    float cmax = -INFINITY;
#pragma unroll
    for (int i = 0; i < CHUNK; ++i) {
      qk[i] = -INFINITY;
      if (i < cnt) {
        int s = csr_src[t0 + i];
        srcs[i] = s;
        uint4 kk = kb_base[(size_t)s * (ROW / 8) + lane];
        float kf[8];
        bf8_unpack(kk, kf);
        float p = q0.x * kf[0] + q0.y * kf[1] + q0.z * kf[2] + q0.w * kf[3] +
                  q1.x * kf[4] + q1.y * kf[5] + q1.z * kf[6] + q1.w * kf[7];
        p += __shfl_xor(p, 1);
        p += __shfl_xor(p, 2);
        p += __shfl_xor(p, 4);
        p *= 0.125f;  // softmax_temp = 1/sqrt(64)
        qk[i] = p;
        cmax = fmaxf(cmax, p);
      }
    }
    float mnew = fmaxf(m, cmax);
    float scale = __expf(m - mnew);  // first chunk: exp(-inf) = 0
    l_run *= scale;
#pragma unroll
    for (int i = 0; i < 8; ++i) acc[i] *= scale;
    m = mnew;
#pragma unroll
    for (int i = 0; i < CHUNK; ++i) {
      if (i < cnt) {
        float a = __expf(qk[i] - m);
        l_run += a;
        uint4 vv = vb_base[(size_t)srcs[i] * (ROW / 8) + lane];
        float vf[8];
        bf8_unpack(vv, vf);
#pragma unroll
        for (int j = 0; j < 8; ++j) acc[j] += a * vf[j];
      }
    }
  }
  float r = 1.0f / (l_run + 1e-16f);  // empty segment: acc=0 -> out=0
  float4* orow = (float4*)(out + ((size_t)b * L + d) * ROW);
  orow[lane * 2 + 0] = make_float4(acc[0] * r, acc[1] * r, acc[2] * r, acc[3] * r);
  orow[lane * 2 + 1] = make_float4(acc[4] * r, acc[5] * r, acc[6] * r, acc[7] * r);
}

extern "C" void kernel_launch(void* const* d_in, const int* in_sizes, int n_in,
                              void* d_out, int out_size, void* d_ws, size_t ws_size,
                              hipStream_t stream) {
  const float* q = (const float*)d_in[0];
  const float* k = (const float*)d_in[1];
  const float* v = (const float*)d_in[2];
  const int* adj = (const int*)d_in[3];

  const int NE = in_sizes[3] / 2;
  const int L = in_sizes[0] / (BB * HH * EE);
  const int* dst = adj;
  const int* src = adj + NE;
  const int nelem = BB * L * HH * EE;  // elements in each of q/k/v

  // workspace layout
  char* ws = (char*)d_ws;
  size_t off = 0;
  unsigned short* kbf = (unsigned short*)(ws + off); off += (size_t)nelem * 2;  // 20.5 MB
  unsigned short* vbf = (unsigned short*)(ws + off); off += (size_t)nelem * 2;  // 20.5 MB
  int* counts = (int*)(ws + off);   off += (size_t)L * 4;
  int* offsets = (int*)(ws + off);  off += (size_t)(L + 1) * 4;
  int* cursor = (int*)(ws + off);   off += (size_t)L * 4;
  int* csr_src = (int*)(ws + off);  off += (size_t)NE * 4;

  hipMemsetAsync(counts, 0, (size_t)L * 4, stream);
  hipMemsetAsync(cursor, 0, (size_t)L * 4, stream);

  // k/v -> bf16
  int n4 = nelem / 4;
  convert_kernel<<<(n4 + 255) / 256, 256, 0, stream>>>(k, v, kbf, vbf, n4);

  // CSR build
  hist_kernel<<<(NE + 255) / 256, 256, 0, stream>>>(dst, counts, NE);
  scan_kernel<<<1, 1024, 0, stream>>>(counts, offsets, L);
  fill_csr_kernel<<<(NE + 255) / 256, 256, 0, stream>>>(dst, src, offsets, cursor, csr_src, NE);

  // fused attention: one wave per (dst, b)
  int nwaves = L * BB;
  fused_attn_kernel<<<(nwaves + 3) / 4, 256, 0, stream>>>(
      q, kbf, vbf, offsets, csr_src, (float*)d_out, L);
}

// Round 4
// 283.702 us; speedup vs baseline: 16.3715x; 1.0143x over previous
//
#include <hip/hip_runtime.h>

// Problem constants (from reference setup_inputs): B=2, L=10000, H=8, E=64, NE=160000
#define BB 2
#define HH 8
#define EE 64
#define ROW (HH * EE)      // 512 elements per (b, node) row
#define CHUNK 8

// ---------- fp32 -> bf16 (RNE) ----------
__device__ inline unsigned short f2bf(float f) {
  unsigned int u = __float_as_uint(f);
  u = (u + 0x7fffu + ((u >> 16) & 1u)) >> 16;
  return (unsigned short)u;
}

// convert k,v to bf16; threads [0, NE) also histogram dst into counts
// (counts zeroed by the preceding memset; stream order guarantees visibility)
__global__ __launch_bounds__(256) void convert_hist_kernel(
    const float* __restrict__ k, const float* __restrict__ v,
    unsigned short* __restrict__ kbf, unsigned short* __restrict__ vbf,
    const int* __restrict__ dst, int* __restrict__ counts,
    int n4, int NE) {
  int i = blockIdx.x * blockDim.x + threadIdx.x;
  if (i < n4) {
    float4 kf = ((const float4*)k)[i];
    float4 vf = ((const float4*)v)[i];
    ((ushort4*)kbf)[i] = make_ushort4(f2bf(kf.x), f2bf(kf.y), f2bf(kf.z), f2bf(kf.w));
    ((ushort4*)vbf)[i] = make_ushort4(f2bf(vf.x), f2bf(vf.y), f2bf(vf.z), f2bf(vf.w));
  }
  if (i < NE) {
    atomicAdd(&counts[dst[i]], 1);
  }
}

// single-block scan: counts -> offsets[0..L]; then zero counts (reused as cursor)
__global__ __launch_bounds__(1024) void scan_kernel(
    const int* __restrict__ counts_in, int* __restrict__ counts_mut,
    int* __restrict__ offsets, int L) {
  __shared__ int sums[1024];
  int tid = threadIdx.x;
  int chunk = (L + 1023) / 1024;
  int beg = tid * chunk;
  int end = min(beg + chunk, L);
  int s = 0;
  for (int i = beg; i < end; ++i) s += counts_in[i];
  sums[tid] = s;
  __syncthreads();
  for (int off = 1; off < 1024; off <<= 1) {
    int val = 0;
    if (tid >= off) val = sums[tid - off];
    __syncthreads();
    if (tid >= off) sums[tid] += val;
    __syncthreads();
  }
  int run = (tid > 0) ? sums[tid - 1] : 0;
  for (int i = beg; i < end; ++i) {
    offsets[i] = run;
    run += counts_in[i];
    counts_mut[i] = 0;  // reuse as cursor in fill
  }
  if (tid == 1023) offsets[L] = run;
}

__global__ __launch_bounds__(256) void fill_csr_kernel(
    const int* __restrict__ dst, const int* __restrict__ src,
    const int* __restrict__ offsets, int* __restrict__ cursor,
    int* __restrict__ csr_src, int NE) {
  int e = blockIdx.x * blockDim.x + threadIdx.x;
  if (e >= NE) return;
  int d = dst[e];
  int pos = atomicAdd(&cursor[d], 1);
  csr_src[offsets[d] + pos] = src[e];
}

// ---------- fused flash-style kernel: one wave per (dst, b) ----------
// lane = h*8 + j covers elements 8*lane .. 8*lane+7 of the 512-elem [H,E] row.
__device__ inline void bf8_unpack(uint4 u, float* f) {
  f[0] = __uint_as_float(u.x << 16);
  f[1] = __uint_as_float(u.x & 0xffff0000u);
  f[2] = __uint_as_float(u.y << 16);
  f[3] = __uint_as_float(u.y & 0xffff0000u);
  f[4] = __uint_as_float(u.z << 16);
  f[5] = __uint_as_float(u.z & 0xffff0000u);
  f[6] = __uint_as_float(u.w << 16);
  f[7] = __uint_as_float(u.w & 0xffff0000u);
}

__global__ __launch_bounds__(256) void fused_attn_kernel(
    const float* __restrict__ q, const unsigned short* __restrict__ kbf,
    const unsigned short* __restrict__ vbf, const int* __restrict__ offsets,
    const int* __restrict__ csr_src, float* __restrict__ out, int L) {
  int wid = blockIdx.x * (blockDim.x >> 6) + (threadIdx.x >> 6);
  int lane = threadIdx.x & 63;
  if (wid >= L * BB) return;
  int d = wid >> 1;
  int b = wid & 1;
  int beg = offsets[d];
  int end = offsets[d + 1];

  const float4* qrow = (const float4*)(q + ((size_t)b * L + d) * ROW);
  float4 q0 = qrow[lane * 2 + 0];
  float4 q1 = qrow[lane * 2 + 1];

  float m = -INFINITY;
  float l_run = 0.0f;
  float acc[8];
#pragma unroll
  for (int i = 0; i < 8; ++i) acc[i] = 0.0f;

  const uint4* kb_base = (const uint4*)(kbf + (size_t)b * L * ROW);
  const uint4* vb_base = (const uint4*)(vbf + (size_t)b * L * ROW);

  for (int t0 = beg; t0 < end; t0 += CHUNK) {
    int cnt = min(CHUNK, end - t0);
    // load phase: issue k AND v gathers for the whole chunk together
    uint4 kk[CHUNK], vv[CHUNK];
#pragma unroll
    for (int i = 0; i < CHUNK; ++i) {
      if (i < cnt) {
        int s = csr_src[t0 + i];
        kk[i] = kb_base[(size_t)s * (ROW / 8) + lane];
        vv[i] = vb_base[(size_t)s * (ROW / 8) + lane];
      }
    }
    // qk phase
    float qk[CHUNK];
    float cmax = -INFINITY;
#pragma unroll
    for (int i = 0; i < CHUNK; ++i) {
      qk[i] = -INFINITY;
      if (i < cnt) {
        float kf[8];
        bf8_unpack(kk[i], kf);
        float p = q0.x * kf[0] + q0.y * kf[1] + q0.z * kf[2] + q0.w * kf[3] +
                  q1.x * kf[4] + q1.y * kf[5] + q1.z * kf[6] + q1.w * kf[7];
        p += __shfl_xor(p, 1);
        p += __shfl_xor(p, 2);
        p += __shfl_xor(p, 4);
        p *= 0.125f;  // softmax_temp = 1/sqrt(64)
        qk[i] = p;
        cmax = fmaxf(cmax, p);
      }
    }
    // online-softmax rescale
    float mnew = fmaxf(m, cmax);
    float scale = __expf(m - mnew);  // first chunk: exp(-inf)=0
    l_run *= scale;
#pragma unroll
    for (int i = 0; i < 8; ++i) acc[i] *= scale;
    m = mnew;
    // accumulate phase (v already in registers)
#pragma unroll
    for (int i = 0; i < CHUNK; ++i) {
      if (i < cnt) {
        float a = __expf(qk[i] - m);
        l_run += a;
        float vf[8];
        bf8_unpack(vv[i], vf);
#pragma unroll
        for (int j = 0; j < 8; ++j) acc[j] += a * vf[j];
      }
    }
  }
  float r = 1.0f / (l_run + 1e-16f);  // empty segment: acc=0 -> out=0
  float4* orow = (float4*)(out + ((size_t)b * L + d) * ROW);
  orow[lane * 2 + 0] = make_float4(acc[0] * r, acc[1] * r, acc[2] * r, acc[3] * r);
  orow[lane * 2 + 1] = make_float4(acc[4] * r, acc[5] * r, acc[6] * r, acc[7] * r);
}

extern "C" void kernel_launch(void* const* d_in, const int* in_sizes, int n_in,
                              void* d_out, int out_size, void* d_ws, size_t ws_size,
                              hipStream_t stream) {
  const float* q = (const float*)d_in[0];
  const float* k = (const float*)d_in[1];
  const float* v = (const float*)d_in[2];
  const int* adj = (const int*)d_in[3];

  const int NE = in_sizes[3] / 2;
  const int L = in_sizes[0] / (BB * HH * EE);
  const int* dst = adj;
  const int* src = adj + NE;
  const int nelem = BB * L * HH * EE;

  // workspace layout
  char* ws = (char*)d_ws;
  size_t off = 0;
  unsigned short* kbf = (unsigned short*)(ws + off); off += (size_t)nelem * 2;
  unsigned short* vbf = (unsigned short*)(ws + off); off += (size_t)nelem * 2;
  int* counts = (int*)(ws + off);   off += (size_t)L * 4;   // doubles as cursor
  int* offsets = (int*)(ws + off);  off += (size_t)(L + 1) * 4;
  int* csr_src = (int*)(ws + off);  off += (size_t)NE * 4;

  hipMemsetAsync(counts, 0, (size_t)L * 4, stream);

  int n4 = nelem / 4;
  convert_hist_kernel<<<(n4 + 255) / 256, 256, 0, stream>>>(
      k, v, kbf, vbf, dst, counts, n4, NE);

  scan_kernel<<<1, 1024, 0, stream>>>(counts, counts, offsets, L);

  fill_csr_kernel<<<(NE + 255) / 256, 256, 0, stream>>>(
      dst, src, offsets, counts, csr_src, NE);

  int nwaves = L * BB;
  fused_attn_kernel<<<(nwaves + 3) / 4, 256, 0, stream>>>(
      q, kbf, vbf, offsets, csr_src, (float*)d_out, L);
}